// Round 1
// baseline (412.635 us; speedup 1.0000x reference)
//
#include <hip/hip_runtime.h>
#include <cstdint>
#include <cstddef>

#define IN_F 8192
#define OUT_F 8192
#define BATCH 512

typedef __bf16 bf16x8 __attribute__((ext_vector_type(8)));
typedef float floatx4 __attribute__((ext_vector_type(4)));

// fp32 -> bf16 round-to-nearest-even (inputs are finite normals)
__device__ __forceinline__ ushort f2bf(float f) {
  uint32_t u = __float_as_uint(f);
  u += 0x7FFFu + ((u >> 16) & 1u);
  return (ushort)(u >> 16);
}

// Pass 1: x fp32 -> bf16 workspace, plus rowsum[b] = sum_k bf16(x[b,k]) in fp32.
// rowsum is computed from the CONVERTED values so the +136 bias in the GEMM
// cancels exactly (up to fp32 accumulation noise).
__global__ __launch_bounds__(256) void cvt_rowsum(const float* __restrict__ x,
                                                  ushort* __restrict__ xb,
                                                  float* __restrict__ rowsum) {
  const int b = blockIdx.x;
  const int t = threadIdx.x;
  const float4* xr = (const float4*)(x + (size_t)b * IN_F);
  ushort4* xo = (ushort4*)(xb + (size_t)b * IN_F);
  float s = 0.f;
#pragma unroll
  for (int i = 0; i < 8; ++i) {
    float4 v = xr[i * 256 + t];
    ushort4 o;
    o.x = f2bf(v.x); o.y = f2bf(v.y); o.z = f2bf(v.z); o.w = f2bf(v.w);
    xo[i * 256 + t] = o;
    s += __uint_as_float((uint32_t)o.x << 16) + __uint_as_float((uint32_t)o.y << 16)
       + __uint_as_float((uint32_t)o.z << 16) + __uint_as_float((uint32_t)o.w << 16);
  }
#pragma unroll
  for (int off = 32; off >= 1; off >>= 1) s += __shfl_down(s, off, 64);
  __shared__ float red[4];
  if ((t & 63) == 0) red[t >> 6] = s;
  __syncthreads();
  if (t == 0) rowsum[b] = red[0] + red[1] + red[2] + red[3];
}

__device__ __forceinline__ void async_copy16(const void* g, void* l) {
  __builtin_amdgcn_global_load_lds((__attribute__((address_space(1))) void*)(g),
                                   (__attribute__((address_space(3))) void*)(l),
                                   16, 0, 0);
}

// Nibble pair -> packed bf16x2 of BIASED values (128+hi, 128+lo) = (q+136).
// 0x4300 | n is exactly bf16(128+n) for n in [0,15] (ulp at 128 is 1).
// hi nibble -> even k (low half), lo nibble -> odd k (high half).
__device__ __forceinline__ uint32_t dq(int p) {
  uint32_t u = (uint32_t)p;
  return (((u >> 4) & 0xFu) | ((u & 0xFu) << 16)) | 0x43004300u;
}

// GEMM: out[m, n] = scale[n] * (sum_k xb[m,k]*(q[n,k]+136) - 136*rowsum[m])
// 128x128 tile, BK=32, 256 threads = 4 waves, each wave a 64x64 quadrant of
// 4x4 mfma_f32_16x16x32_bf16 accumulators. A staged via global_load_lds (16B),
// B staged via VGPR unpack of packed int4 -> biased bf16 -> ds_write_b128.
__global__ __launch_bounds__(256) void qgemm(const ushort* __restrict__ xb,
                                             const int* __restrict__ pw,
                                             const float* __restrict__ scale,
                                             const float* __restrict__ rowsum,
                                             float* __restrict__ out) {
  __shared__ uint32_t As[128 * 16];  // 128 rows x 32 bf16 (64 B rows), 8 KB
  __shared__ uint32_t Bs[128 * 16];  // 128 rows x 32 bf16, 8 KB

  const int tid = threadIdx.x;
  const int lane = tid & 63;
  const int w = tid >> 6;           // wave 0..3
  const int wm = w & 1;             // wave row-half of the 128x128 tile
  const int wn = w >> 1;            // wave col-half
  const int lr = lane & 15;
  const int lq = lane >> 4;

  const int n0 = blockIdx.x * 128;  // out-feature tile
  const int m0 = blockIdx.y * 128;  // batch tile

  // ---- A staging addresses (global_load_lds, 16 B/lane) ----
  // wave w owns tile rows [w*32, w*32+32): two instructions of 16 rows each.
  // lane L -> row base + L/4, byte chunk (L&3)*16; LDS dst = base + L*16. Exact match.
  const int ar0 = w * 32 + (lane >> 2);
  const int ac = (lane & 3) * 8;                       // ushort offset in row
  const ushort* ag0 = xb + (size_t)(m0 + ar0) * IN_F + ac;
  const ushort* ag1 = ag0 + (size_t)16 * IN_F;
  uint32_t* al0 = As + w * 512;                        // byte base w*2048
  uint32_t* al1 = al0 + 256;                           // +1024 B (16 rows)

  // ---- B staging addresses ----
  // thread t -> weight row n = t>>1, half h = t&1 (8 int32 = 16 k-values each)
  const int bn = tid >> 1;
  const int bh = tid & 1;
  const int4* bgp = (const int4*)(pw + (size_t)(n0 + bn) * (IN_F / 2) + bh * 8);
  uint32_t* bws = Bs + bn * 16 + bh * 8;

  floatx4 acc[4][4] = {};

  const uint32_t* arow = As + (wm * 64 + lr) * 16 + lq * 4;
  const uint32_t* brow = Bs + (wn * 64 + lr) * 16 + lq * 4;

  for (int k0 = 0; k0 < IN_F; k0 += 32) {
    __syncthreads();  // previous compute done reading LDS
    // B global loads first (deepest latency), then A fire-and-forget asyncs.
    int4 p0 = bgp[0];
    int4 p1 = bgp[1];
    bgp += 4;  // advance 16 int32 (= 32 k) per step
    async_copy16(ag0 + k0, al0);
    async_copy16(ag1 + k0, al1);
    // unpack 8 int32 -> 16 biased bf16 (32 B) and write to LDS
    int4 u0, u1;
    u0.x = dq(p0.x); u0.y = dq(p0.y); u0.z = dq(p0.z); u0.w = dq(p0.w);
    u1.x = dq(p1.x); u1.y = dq(p1.y); u1.z = dq(p1.z); u1.w = dq(p1.w);
    ((int4*)bws)[0] = u0;
    ((int4*)bws)[1] = u1;
    __syncthreads();  // compiler drains vmcnt (lds-loads) + lgkm (ds_write)

    bf16x8 av[4], bv[4];
#pragma unroll
    for (int i = 0; i < 4; ++i) av[i] = *(const bf16x8*)(arow + i * 256);
#pragma unroll
    for (int i = 0; i < 4; ++i) bv[i] = *(const bf16x8*)(brow + i * 256);
#pragma unroll
    for (int mi = 0; mi < 4; ++mi)
#pragma unroll
      for (int ni = 0; ni < 4; ++ni)
        acc[mi][ni] = __builtin_amdgcn_mfma_f32_16x16x32_bf16(av[mi], bv[ni],
                                                              acc[mi][ni], 0, 0, 0);
  }

  // ---- epilogue ----
  // C/D layout: col = lane&15, row = (lane>>4)*4 + reg  [verified m89/m91]
  const int om = m0 + wm * 64 + lq * 4;
  const int on = n0 + wn * 64 + lr;
  float scv[4];
#pragma unroll
  for (int ni = 0; ni < 4; ++ni) scv[ni] = scale[on + ni * 16];
  float rsv[4][4];
#pragma unroll
  for (int mi = 0; mi < 4; ++mi)
#pragma unroll
    for (int r = 0; r < 4; ++r) rsv[mi][r] = rowsum[om + mi * 16 + r];

#pragma unroll
  for (int mi = 0; mi < 4; ++mi)
#pragma unroll
    for (int ni = 0; ni < 4; ++ni) {
      float s = scv[ni];
      float* op = out + (size_t)(om + mi * 16) * OUT_F + (on + ni * 16);
#pragma unroll
      for (int r = 0; r < 4; ++r)
        op[(size_t)r * OUT_F] = s * (acc[mi][ni][r] - 136.f * rsv[mi][r]);
    }
}

extern "C" void kernel_launch(void* const* d_in, const int* in_sizes, int n_in,
                              void* d_out, int out_size, void* d_ws, size_t ws_size,
                              hipStream_t stream) {
  const float* x = (const float*)d_in[0];
  const int* pw = (const int*)d_in[1];
  const float* scale = (const float*)d_in[2];
  float* out = (float*)d_out;

  // workspace: bf16 x copy (8 MiB) + rowsum (2 KiB)
  ushort* xb = (ushort*)d_ws;
  float* rowsum = (float*)((char*)d_ws + (size_t)BATCH * IN_F * sizeof(ushort));

  cvt_rowsum<<<BATCH, 256, 0, stream>>>(x, xb, rowsum);
  dim3 grid(OUT_F / 128, BATCH / 128);
  qgemm<<<grid, 256, 0, stream>>>(xb, pw, scale, rowsum, out);
}

// Round 2
// 309.506 us; speedup vs baseline: 1.3332x; 1.3332x over previous
//
#include <hip/hip_runtime.h>
#include <cstdint>
#include <cstddef>

#define IN_F 8192
#define OUT_F 8192
#define BATCH 512
#define KSPLIT 4
#define KSLICE (IN_F / KSPLIT) /* 2048 */
#define BK 32
#define NIT (KSLICE / BK) /* 64 */

typedef __bf16 bf16x8 __attribute__((ext_vector_type(8)));
typedef float floatx4 __attribute__((ext_vector_type(4)));

// fp32 -> bf16 round-to-nearest-even
__device__ __forceinline__ ushort f2bf(float f) {
  uint32_t u = __float_as_uint(f);
  u += 0x7FFFu + ((u >> 16) & 1u);
  return (ushort)(u >> 16);
}

// one byte (2 nibbles) -> packed bf16x2 of biased weights (q+136):
// low half = 0x4300|hi_nibble (even k), high half = 0x4300|lo_nibble (odd k)
__device__ __forceinline__ uint32_t dq(int p) {
  uint32_t u = (uint32_t)p;
  return (((u >> 4) & 0xFu) | ((u & 0xFu) << 16)) | 0x43004300u;
}

// Pass 1: x fp32 -> bf16, plus PER-SLICE rowsums of the converted values:
// rowsum[s*BATCH + b] = sum over k in slice s of bf16(x[b,k]).
__global__ __launch_bounds__(256) void cvt_rowsum(const float* __restrict__ x,
                                                  ushort* __restrict__ xb,
                                                  float* __restrict__ rowsum) {
  const int b = blockIdx.x;
  const int t = threadIdx.x;
  const float4* xr = (const float4*)(x + (size_t)b * IN_F);
  ushort4* xo = (ushort4*)(xb + (size_t)b * IN_F);
  float s[4] = {0.f, 0.f, 0.f, 0.f};
#pragma unroll
  for (int i = 0; i < 8; ++i) {
    float4 v = xr[i * 256 + t];
    ushort4 o;
    o.x = f2bf(v.x); o.y = f2bf(v.y); o.z = f2bf(v.z); o.w = f2bf(v.w);
    xo[i * 256 + t] = o;
    s[i >> 1] += __uint_as_float((uint32_t)o.x << 16) + __uint_as_float((uint32_t)o.y << 16)
               + __uint_as_float((uint32_t)o.z << 16) + __uint_as_float((uint32_t)o.w << 16);
  }
  __shared__ float red[4][4];
  const int lane = t & 63, wid = t >> 6;
#pragma unroll
  for (int j = 0; j < 4; ++j) {
    float v = s[j];
#pragma unroll
    for (int off = 32; off >= 1; off >>= 1) v += __shfl_down(v, off, 64);
    if (lane == 0) red[wid][j] = v;
  }
  __syncthreads();
  if (t < 4) rowsum[t * BATCH + b] = red[0][t] + red[1][t] + red[2][t] + red[3][t];
}

// Split-K quantized GEMM. Block: 128(m) x 128(n) x KSLICE(k), 4 waves of 64x64.
// K-loop: [write tile(it) regs->LDS] [barrier] [issue loads tile(it+1)]
//         [ds_read + 16 MFMA]  -- one barrier/iter, loads never drained by it.
__global__ __launch_bounds__(256, 2) void qgemm(const ushort* __restrict__ xb,
                                                const int* __restrict__ pw,
                                                const float* __restrict__ scale,
                                                const float* __restrict__ rowsum,
                                                float* __restrict__ out) {
  __shared__ uint32_t As[2 * 128 * 16];  // 2 bufs x 128 rows x 32 bf16, 16 KB
  __shared__ uint32_t Bs[2 * 128 * 16];  // 16 KB

  const int tid = threadIdx.x;
  const int lane = tid & 63;
  const int w = tid >> 6;
  const int wm = w & 1, wn = w >> 1;
  const int lr = lane & 15, lq = lane >> 4;

  const int n0 = blockIdx.x * 128;
  const int m0 = blockIdx.y * 128;
  const int ks = blockIdx.z;

  // global staging: thread t -> tile row r = t>>1, 32-byte half h = t&1
  const int r = tid >> 1, h = tid & 1;
  const char* aG = (const char*)xb + (size_t)(m0 + r) * (IN_F * 2) + ks * (KSLICE * 2) + h * 32;
  const char* bG = (const char*)pw + (size_t)(n0 + r) * (IN_F * 2) + ks * (KSLICE * 2) + h * 32;

  uint32_t* aW = As + r * 16 + h * 8;
  uint32_t* bW = Bs + r * 16 + h * 8;
  const uint32_t* aR = As + (wm * 64 + lr) * 16 + lq * 4;
  const uint32_t* bR = Bs + (wn * 64 + lr) * 16 + lq * 4;

  floatx4 acc[4][4] = {};

  // preload tile 0 into regs
  int4 pa0 = *(const int4*)(aG);
  int4 pa1 = *(const int4*)(aG + 16);
  int4 pb0 = *(const int4*)(bG);
  int4 pb1 = *(const int4*)(bG + 16);
  aG += 64; bG += 64;

  for (int it = 0; it < NIT; ++it) {
    const int off = (it & 1) * (128 * 16);
    // stage tile(it): A copy, B unpack -> biased bf16
    *(int4*)(aW + off) = pa0;
    *(int4*)(aW + off + 4) = pa1;
    int4 u0, u1;
    u0.x = dq(pb0.x); u0.y = dq(pb0.y); u0.z = dq(pb0.z); u0.w = dq(pb0.w);
    u1.x = dq(pb1.x); u1.y = dq(pb1.y); u1.z = dq(pb1.z); u1.w = dq(pb1.w);
    *(int4*)(bW + off) = u0;
    *(int4*)(bW + off + 4) = u1;
    __syncthreads();  // vmcnt already 0 here (loads were consumed by the writes)
    // prefetch tile(it+1) into regs; a full compute phase to land
    if (it + 1 < NIT) {
      pa0 = *(const int4*)(aG);
      pa1 = *(const int4*)(aG + 16);
      pb0 = *(const int4*)(bG);
      pb1 = *(const int4*)(bG + 16);
      aG += 64; bG += 64;
    }
    // compute tile(it)
    bf16x8 av[4], bv[4];
#pragma unroll
    for (int i = 0; i < 4; ++i) av[i] = *(const bf16x8*)(aR + off + i * 256);
#pragma unroll
    for (int i = 0; i < 4; ++i) bv[i] = *(const bf16x8*)(bR + off + i * 256);
#pragma unroll
    for (int mi = 0; mi < 4; ++mi)
#pragma unroll
      for (int ni = 0; ni < 4; ++ni)
        acc[mi][ni] = __builtin_amdgcn_mfma_f32_16x16x32_bf16(av[mi], bv[ni],
                                                              acc[mi][ni], 0, 0, 0);
  }

  // epilogue: C/D layout col=lane&15, row=(lane>>4)*4+reg
  const int om = m0 + wm * 64 + lq * 4;
  const int on = n0 + wn * 64 + lr;
  float scv[4];
#pragma unroll
  for (int ni = 0; ni < 4; ++ni) scv[ni] = scale[on + ni * 16];
  float rsv[4][4];
#pragma unroll
  for (int mi = 0; mi < 4; ++mi)
#pragma unroll
    for (int rr = 0; rr < 4; ++rr)
      rsv[mi][rr] = rowsum[ks * BATCH + om + mi * 16 + rr];

#pragma unroll
  for (int mi = 0; mi < 4; ++mi)
#pragma unroll
    for (int ni = 0; ni < 4; ++ni) {
      const float s = scv[ni];
      float* op = out + (size_t)(om + mi * 16) * OUT_F + (on + ni * 16);
#pragma unroll
      for (int rr = 0; rr < 4; ++rr)
        atomicAdd(op + (size_t)rr * OUT_F, s * (acc[mi][ni][rr] - 136.f * rsv[mi][rr]));
    }
}

extern "C" void kernel_launch(void* const* d_in, const int* in_sizes, int n_in,
                              void* d_out, int out_size, void* d_ws, size_t ws_size,
                              hipStream_t stream) {
  const float* x = (const float*)d_in[0];
  const int* pw = (const int*)d_in[1];
  const float* scale = (const float*)d_in[2];
  float* out = (float*)d_out;

  ushort* xb = (ushort*)d_ws;  // 8 MiB
  float* rowsum = (float*)((char*)d_ws + (size_t)BATCH * IN_F * sizeof(ushort));  // 4x512 f32

  cvt_rowsum<<<BATCH, 256, 0, stream>>>(x, xb, rowsum);
  hipMemsetAsync(out, 0, (size_t)out_size * sizeof(float), stream);
  dim3 grid(OUT_F / 128, BATCH / 128, KSPLIT);
  qgemm<<<grid, 256, 0, stream>>>(xb, pw, scale, rowsum, out);
}